// Round 1
// baseline (673.722 us; speedup 1.0000x reference)
//
#include <hip/hip_runtime.h>

#define NBINS 15

// Pass 1: per-row conf/argmax, per-block 15-bin partial histograms.
// Half-wave (32 lanes) per row: lane reads float4 (16B), 32*16B = 512B = one row (C=128).
// conf = 1/sum(exp(x - max)); pred = argmax(logits) with first-occurrence tie-break.
// Partials: count (u32), correct (u32), conf fixed-point *2^32 (u64) -- exact, deterministic.
__global__ __launch_bounds__(256) void mce_pass1(
    const float* __restrict__ logits, const int* __restrict__ labels,
    unsigned long long* __restrict__ conf_part,
    unsigned int* __restrict__ cnt_part,
    unsigned int* __restrict__ acc_part,
    int n)
{
    __shared__ unsigned int s_cnt[NBINS];
    __shared__ unsigned int s_acc[NBINS];
    __shared__ unsigned long long s_conf[NBINS];
    if (threadIdx.x < NBINS) {
        s_cnt[threadIdx.x] = 0u;
        s_acc[threadIdx.x] = 0u;
        s_conf[threadIdx.x] = 0ULL;
    }
    __syncthreads();

    const int lane32 = threadIdx.x & 31;
    const int hw_global = blockIdx.x * 8 + (threadIdx.x >> 5);  // 8 half-waves per block
    const int hw_total = gridDim.x * 8;

    for (int row = hw_global; row < n; row += hw_total) {
        const float4 v = *(const float4*)(logits + (size_t)row * 128 + lane32 * 4);

        // local max + first-occurrence index
        const int base_i = lane32 * 4;
        float m = v.x; int idx = base_i;
        if (v.y > m) { m = v.y; idx = base_i + 1; }
        if (v.z > m) { m = v.z; idx = base_i + 2; }
        if (v.w > m) { m = v.w; idx = base_i + 3; }

        // 32-lane butterfly argmax (min index on ties -> first occurrence)
        #pragma unroll
        for (int off = 16; off >= 1; off >>= 1) {
            float om = __shfl_xor(m, off, 32);
            int   oi = __shfl_xor(idx, off, 32);
            if (om > m || (om == m && oi < idx)) { m = om; idx = oi; }
        }

        // sum of exp(x - max)
        float s = __expf(v.x - m) + __expf(v.y - m) + __expf(v.z - m) + __expf(v.w - m);
        #pragma unroll
        for (int off = 16; off >= 1; off >>= 1)
            s += __shfl_xor(s, off, 32);

        if (lane32 == 0) {
            float conf = 1.0f / s;
            // searchsorted(uppers, conf, 'left') with uppers[j]=(j+1)/15  ==  ceil(15*conf)-1
            int bin = (int)ceilf(conf * 15.0f) - 1;
            bin = max(0, min(NBINS - 1, bin));
            unsigned int acc = (idx == labels[row]) ? 1u : 0u;
            unsigned long long fc = (unsigned long long)((double)conf * 4294967296.0);
            atomicAdd(&s_cnt[bin], 1u);
            atomicAdd(&s_acc[bin], acc);
            atomicAdd(&s_conf[bin], fc);
        }
    }
    __syncthreads();
    if (threadIdx.x < NBINS) {
        cnt_part[blockIdx.x * NBINS + threadIdx.x]  = s_cnt[threadIdx.x];
        acc_part[blockIdx.x * NBINS + threadIdx.x]  = s_acc[threadIdx.x];
        conf_part[blockIdx.x * NBINS + threadIdx.x] = s_conf[threadIdx.x];
    }
}

// Pass 2: one block, 15 waves; wave w reduces bin w across all B block-partials.
// Fully deterministic (integer sums), then computes avgs/gap/mce and writes 31 floats.
__global__ __launch_bounds__(960) void mce_pass2(
    const unsigned long long* __restrict__ conf_part,
    const unsigned int* __restrict__ cnt_part,
    const unsigned int* __restrict__ acc_part,
    int B, float* __restrict__ out)
{
    __shared__ float s_prob[NBINS], s_accu[NBINS], s_gap[NBINS];
    __shared__ int s_ne[NBINS];

    const int bin  = threadIdx.x >> 6;   // 0..14
    const int lane = threadIdx.x & 63;

    unsigned long long csum = 0ULL;
    unsigned int cn = 0u, ac = 0u;
    for (int i = lane; i < B; i += 64) {
        csum += conf_part[i * NBINS + bin];
        cn   += cnt_part[i * NBINS + bin];
        ac   += acc_part[i * NBINS + bin];
    }
    #pragma unroll
    for (int off = 32; off >= 1; off >>= 1) {
        csum += __shfl_xor(csum, off, 64);
        cn   += __shfl_xor(cn, off, 64);
        ac   += __shfl_xor(ac, off, 64);
    }

    if (lane == 0) {
        if (cn > 0u) {
            float p = (float)(((double)csum * (1.0 / 4294967296.0)) / (double)cn);
            float a = (float)((double)ac / (double)cn);
            s_prob[bin] = p;
            s_accu[bin] = a;
            s_gap[bin]  = fabsf(p - a);
            s_ne[bin]   = 1;
        } else {
            s_prob[bin] = 0.0f;
            s_accu[bin] = 0.0f;
            s_gap[bin]  = 0.0f;
            s_ne[bin]   = 0;
        }
    }
    __syncthreads();

    if (threadIdx.x == 0) {
        float mce = -1e30f;
        for (int b = 0; b < NBINS; ++b)
            if (s_ne[b] && s_gap[b] > mce) mce = s_gap[b];
        out[0] = mce;
    }
    if (threadIdx.x < NBINS) {
        out[1 + threadIdx.x]  = s_prob[threadIdx.x];
        out[16 + threadIdx.x] = s_accu[threadIdx.x];
    }
}

extern "C" void kernel_launch(void* const* d_in, const int* in_sizes, int n_in,
                              void* d_out, int out_size, void* d_ws, size_t ws_size,
                              hipStream_t stream) {
    const float* logits = (const float*)d_in[0];
    const int*   labels = (const int*)d_in[1];
    const int n = in_sizes[1];              // 1e6 rows; C fixed at 128

    int B = 2048;                           // 2048 blocks * 4 waves = 8192 waves = 32/CU
    const size_t per_block = (size_t)NBINS * (8 + 4 + 4);
    if ((size_t)B * per_block > ws_size) B = (int)(ws_size / per_block);
    if (B < 1) B = 1;

    unsigned long long* conf_part = (unsigned long long*)d_ws;
    unsigned int* cnt_part = (unsigned int*)((char*)d_ws + (size_t)B * NBINS * 8);
    unsigned int* acc_part = (unsigned int*)((char*)d_ws + (size_t)B * NBINS * 12);

    mce_pass1<<<B, 256, 0, stream>>>(logits, labels, conf_part, cnt_part, acc_part, n);
    mce_pass2<<<1, 960, 0, stream>>>(conf_part, cnt_part, acc_part, B, (float*)d_out);
}

// Round 2
// 665.717 us; speedup vs baseline: 1.0120x; 1.0120x over previous
//
#include <hip/hip_runtime.h>

#define NBINS 15

// Pass 1: per-row conf/argmax, per-block 15-bin partial histograms.
// Half-wave (32 lanes) per row: lane reads float4 (16B), 32*16B = 512B = one row (C=128).
// conf = 1/sum(exp(x - max)); pred = argmax(logits), first-occurrence tie-break via
// ballot+ffs (lowest lane = lowest index range).
// Partials: count (u32), correct (u32), conf fixed-point *2^32 (u64) -- exact, deterministic.
__global__ __launch_bounds__(256) void mce_pass1(
    const float* __restrict__ logits, const int* __restrict__ labels,
    unsigned long long* __restrict__ conf_part,
    unsigned int* __restrict__ cnt_part,
    unsigned int* __restrict__ acc_part,
    int n)
{
    __shared__ unsigned int s_cnt[NBINS];
    __shared__ unsigned int s_acc[NBINS];
    __shared__ unsigned long long s_conf[NBINS];
    if (threadIdx.x < NBINS) {
        s_cnt[threadIdx.x] = 0u;
        s_acc[threadIdx.x] = 0u;
        s_conf[threadIdx.x] = 0ULL;
    }
    __syncthreads();

    const int lane32 = threadIdx.x & 31;
    const int half   = (threadIdx.x >> 5) & 1;          // which half of the wave
    const int hw_global = blockIdx.x * 8 + (threadIdx.x >> 5);  // 8 half-waves per block
    const int hw_total = gridDim.x * 8;

    for (int row = hw_global; row < n; row += hw_total) {
        const float4 v = *(const float4*)(logits + (size_t)row * 128 + lane32 * 4);
        const int lab = labels[row];                     // broadcast load, overlaps latency

        // lane-local max of 4
        float m4 = fmaxf(fmaxf(v.x, v.y), fmaxf(v.z, v.w));

        // 32-lane butterfly max
        float M = m4;
        #pragma unroll
        for (int off = 16; off >= 1; off >>= 1)
            M = fmaxf(M, __shfl_xor(M, off, 32));

        // argmax: lowest lane whose local max == M; within it, first matching elem.
        int idx_local = (v.x == M) ? 0 : (v.y == M) ? 1 : (v.z == M) ? 2 : 3;
        unsigned long long bal = __ballot(m4 == M);
        unsigned int mask32 = (unsigned int)(bal >> (half << 5));
        int win_lane = __ffs(mask32) - 1;                // >=0: at least one lane matches
        int win_local = __shfl(idx_local, win_lane, 32);
        int pred = (win_lane << 2) + win_local;

        // sum of exp(x - max)
        float s = __expf(v.x - M) + __expf(v.y - M) + __expf(v.z - M) + __expf(v.w - M);
        #pragma unroll
        for (int off = 16; off >= 1; off >>= 1)
            s += __shfl_xor(s, off, 32);

        if (lane32 == 0) {
            float conf = 1.0f / s;
            // searchsorted(uppers, conf, 'left') with uppers[j]=(j+1)/15 == ceil(15*conf)-1
            int bin = (int)ceilf(conf * 15.0f) - 1;
            bin = max(0, min(NBINS - 1, bin));
            unsigned int acc = (pred == lab) ? 1u : 0u;
            unsigned long long fc = (unsigned long long)((double)conf * 4294967296.0);
            atomicAdd(&s_cnt[bin], 1u);
            atomicAdd(&s_acc[bin], acc);
            atomicAdd(&s_conf[bin], fc);
        }
    }
    __syncthreads();
    if (threadIdx.x < NBINS) {
        cnt_part[blockIdx.x * NBINS + threadIdx.x]  = s_cnt[threadIdx.x];
        acc_part[blockIdx.x * NBINS + threadIdx.x]  = s_acc[threadIdx.x];
        conf_part[blockIdx.x * NBINS + threadIdx.x] = s_conf[threadIdx.x];
    }
}

// Pass 2: one block, 15 waves; wave w reduces bin w across all B block-partials.
// Fully deterministic (integer sums), then computes avgs/gap/mce and writes 31 floats.
__global__ __launch_bounds__(960) void mce_pass2(
    const unsigned long long* __restrict__ conf_part,
    const unsigned int* __restrict__ cnt_part,
    const unsigned int* __restrict__ acc_part,
    int B, float* __restrict__ out)
{
    __shared__ float s_prob[NBINS], s_accu[NBINS], s_gap[NBINS];
    __shared__ int s_ne[NBINS];

    const int bin  = threadIdx.x >> 6;   // 0..14
    const int lane = threadIdx.x & 63;

    unsigned long long csum = 0ULL;
    unsigned int cn = 0u, ac = 0u;
    for (int i = lane; i < B; i += 64) {
        csum += conf_part[i * NBINS + bin];
        cn   += cnt_part[i * NBINS + bin];
        ac   += acc_part[i * NBINS + bin];
    }
    #pragma unroll
    for (int off = 32; off >= 1; off >>= 1) {
        csum += __shfl_xor(csum, off, 64);
        cn   += __shfl_xor(cn, off, 64);
        ac   += __shfl_xor(ac, off, 64);
    }

    if (lane == 0) {
        if (cn > 0u) {
            float p = (float)(((double)csum * (1.0 / 4294967296.0)) / (double)cn);
            float a = (float)((double)ac / (double)cn);
            s_prob[bin] = p;
            s_accu[bin] = a;
            s_gap[bin]  = fabsf(p - a);
            s_ne[bin]   = 1;
        } else {
            s_prob[bin] = 0.0f;
            s_accu[bin] = 0.0f;
            s_gap[bin]  = 0.0f;
            s_ne[bin]   = 0;
        }
    }
    __syncthreads();

    if (threadIdx.x == 0) {
        float mce = -1e30f;
        for (int b = 0; b < NBINS; ++b)
            if (s_ne[b] && s_gap[b] > mce) mce = s_gap[b];
        out[0] = mce;
    }
    if (threadIdx.x < NBINS) {
        out[1 + threadIdx.x]  = s_prob[threadIdx.x];
        out[16 + threadIdx.x] = s_accu[threadIdx.x];
    }
}

extern "C" void kernel_launch(void* const* d_in, const int* in_sizes, int n_in,
                              void* d_out, int out_size, void* d_ws, size_t ws_size,
                              hipStream_t stream) {
    const float* logits = (const float*)d_in[0];
    const int*   labels = (const int*)d_in[1];
    const int n = in_sizes[1];              // 1e6 rows; C fixed at 128

    int B = 2048;                           // 2048 blocks * 4 waves = 8192 waves = 32/CU
    const size_t per_block = (size_t)NBINS * (8 + 4 + 4);
    if ((size_t)B * per_block > ws_size) B = (int)(ws_size / per_block);
    if (B < 1) B = 1;

    unsigned long long* conf_part = (unsigned long long*)d_ws;
    unsigned int* cnt_part = (unsigned int*)((char*)d_ws + (size_t)B * NBINS * 8);
    unsigned int* acc_part = (unsigned int*)((char*)d_ws + (size_t)B * NBINS * 12);

    mce_pass1<<<B, 256, 0, stream>>>(logits, labels, conf_part, cnt_part, acc_part, n);
    mce_pass2<<<1, 960, 0, stream>>>(conf_part, cnt_part, acc_part, B, (float*)d_out);
}